// Round 1
// baseline (350.295 us; speedup 1.0000x reference)
//
#include <hip/hip_runtime.h>

#define DIM 64
#define SLOPE 0.01f

// ---------------------------------------------------------------------------
// Kernel 1: per-node projections.
// One thread per node. v row lives in VGPRs; Wa/Wg rows are wave-uniform
// addresses -> compiler emits s_load + FMA-with-SGPR-operand.
// Outputs: z = v@Wa.T, u = v@Wg.T, s_l = z.a_l, s_r = z.a_r, t = v.gr, g0 = v.gl
// ---------------------------------------------------------------------------
__global__ __launch_bounds__(256) void node_proj(
    const float* __restrict__ v, const float* __restrict__ Wa,
    const float* __restrict__ Wg, const float* __restrict__ a_l,
    const float* __restrict__ a_r, const float* __restrict__ gl,
    const float* __restrict__ gr,
    float* __restrict__ z, float* __restrict__ u,
    float* __restrict__ s_l, float* __restrict__ s_r,
    float* __restrict__ t_gr, float* __restrict__ g0, int N)
{
    int n = blockIdx.x * 256 + threadIdx.x;
    if (n >= N) return;
    float vr[DIM];
    const float4* vp = (const float4*)(v + (size_t)n * DIM);
#pragma unroll
    for (int i = 0; i < DIM / 4; i++) {
        float4 q = vp[i];
        vr[4 * i + 0] = q.x; vr[4 * i + 1] = q.y;
        vr[4 * i + 2] = q.z; vr[4 * i + 3] = q.w;
    }
    float sl = 0.f, sr = 0.f;
#pragma unroll 2
    for (int k = 0; k < DIM; k++) {
        const float* war = Wa + k * DIM;   // wave-uniform
        const float* wgr = Wg + k * DIM;   // wave-uniform
        float zk = 0.f, uk = 0.f;
#pragma unroll
        for (int i = 0; i < DIM; i++) {
            zk += vr[i] * war[i];
            uk += vr[i] * wgr[i];
        }
        z[(size_t)n * DIM + k] = zk;
        u[(size_t)n * DIM + k] = uk;
        sl += zk * a_l[k];
        sr += zk * a_r[k];
    }
    float tg = 0.f, gg = 0.f;
#pragma unroll
    for (int i = 0; i < DIM; i++) { tg += vr[i] * gr[i]; gg += vr[i] * gl[i]; }
    s_l[n] = sl; s_r[n] = sr; t_gr[n] = tg; g0[n] = gg;
}

// ---------------------------------------------------------------------------
// CSR build: count -> scan (3 small kernels) -> scatter
// ---------------------------------------------------------------------------
__global__ __launch_bounds__(256) void count_edges(
    const int* __restrict__ dst, int* __restrict__ cnt, int E)
{
    int e = blockIdx.x * 256 + threadIdx.x;
    if (e < E) atomicAdd(&cnt[dst[e]], 1);
}

// per-1024-chunk sums
__global__ __launch_bounds__(256) void scan_reduce(
    const int* __restrict__ cnt, int* __restrict__ bsum, int N)
{
    __shared__ int lds[256];
    int base = blockIdx.x * 1024;
    int s = 0;
    for (int i = threadIdx.x; i < 1024; i += 256) {
        int idx = base + i;
        if (idx < N) s += cnt[idx];
    }
    lds[threadIdx.x] = s;
    __syncthreads();
    for (int off = 128; off; off >>= 1) {
        if (threadIdx.x < off) lds[threadIdx.x] += lds[threadIdx.x + off];
        __syncthreads();
    }
    if (threadIdx.x == 0) bsum[blockIdx.x] = lds[0];
}

// exclusive scan of block sums (nb <= 64 here: N=50000 -> nb=49)
__global__ void scan_bsum(int* __restrict__ bsum, int nb)
{
    int i = threadIdx.x;
    int x = (i < nb) ? bsum[i] : 0;
    int incl = x;
    for (int off = 1; off < 64; off <<= 1) {
        int y = __shfl_up(incl, off, 64);
        if (i >= off) incl += y;
    }
    if (i < nb) bsum[i] = incl - x;
}

// per-chunk exclusive scan + add chunk offset; writes offs and cursor copy
__global__ __launch_bounds__(256) void scan_final(
    const int* __restrict__ cnt, const int* __restrict__ bsum,
    int* __restrict__ offs, int* __restrict__ cursor, int N)
{
    __shared__ int lds[256];
    int base = blockIdx.x * 1024;
    int t = threadIdx.x;
    int idx0 = base + t * 4;
    int v4[4];
    int s = 0;
#pragma unroll
    for (int j = 0; j < 4; j++) {
        int idx = idx0 + j;
        int c = (idx < N) ? cnt[idx] : 0;
        v4[j] = s;
        s += c;
    }
    lds[t] = s;
    __syncthreads();
    for (int off = 1; off < 256; off <<= 1) {
        int y = (t >= off) ? lds[t - off] : 0;
        __syncthreads();
        lds[t] += y;
        __syncthreads();
    }
    int excl = lds[t] - s + bsum[blockIdx.x];
#pragma unroll
    for (int j = 0; j < 4; j++) {
        int idx = idx0 + j;
        if (idx < N) {
            int o = excl + v4[j];
            offs[idx] = o;
            cursor[idx] = o;
        }
    }
}

// scatter edges into CSR order; fuse the edge attention score (pre-leaky_relu
// reductions already folded into per-node scalars s_l/s_r)
__global__ __launch_bounds__(256) void scatter_edges(
    const int* __restrict__ src, const int* __restrict__ dst,
    const float* __restrict__ pre_w,
    const float* __restrict__ s_l, const float* __restrict__ s_r,
    int* __restrict__ cursor,
    int* __restrict__ src_s, float* __restrict__ pw_s, float* __restrict__ e_s,
    int E)
{
    int e = blockIdx.x * 256 + threadIdx.x;
    if (e >= E) return;
    int s = src[e], d = dst[e];
    float pw = pre_w[e];
    int pos = atomicAdd(&cursor[d], 1);
    float ea = pw * s_l[s] + s_r[d];
    ea = ea > 0.f ? ea : SLOPE * ea;   // leaky_relu
    src_s[pos] = s;
    pw_s[pos] = pw;
    e_s[pos] = ea;
}

// ---------------------------------------------------------------------------
// Kernel 5: one wave per dst node, lane = feature dim.
// Online softmax over in-edges + per-dim max of pre_w*u[src] + scalar mean,
// then fused gate (sigmoid) and normalized store.
// ---------------------------------------------------------------------------
__global__ __launch_bounds__(256) void aggregate(
    const int* __restrict__ offs, const int* __restrict__ cnt,
    const int* __restrict__ src_s, const float* __restrict__ pw_s,
    const float* __restrict__ e_s,
    const float* __restrict__ z, const float* __restrict__ u,
    const float* __restrict__ t_gr, const float* __restrict__ g0,
    const float* __restrict__ gm,
    float* __restrict__ out, int N)
{
    int wid = (blockIdx.x * 256 + threadIdx.x) >> 6;
    int k = threadIdx.x & 63;
    if (wid >= N) return;
    int n = wid;
    int deg = cnt[n];
    size_t outIdx = (size_t)n * DIM + k;
    if (deg == 0) { out[outIdx] = 0.f; return; }
    int start = offs[n];

    float m = -INFINITY, denom = 0.f, hk = 0.f, mfk = -INFINITY, msum = 0.f;
    for (int j = 0; j < deg; j++) {
        int p = start + j;
        int s = src_s[p];
        float pw = pw_s[p];
        float ea = e_s[p];
        float zs = z[(size_t)s * DIM + k];   // 256B coalesced gather
        float us = u[(size_t)s * DIM + k];   // 256B coalesced gather
        float mnew = fmaxf(m, ea);
        float scale = __expf(m - mnew);      // exp(-inf) = 0 on first iter
        float w = __expf(ea - mnew);
        denom = denom * scale + w;
        hk = hk * scale + w * zs;
        m = mnew;
        mfk = fmaxf(mfk, pw * us);
        msum += pw * t_gr[s];
    }
    // wave reduction: maxFeat . gm
    float r = gm[k] * mfk;
    for (int off = 32; off; off >>= 1) r += __shfl_down(r, off, 64);
    r = __shfl(r, 0, 64);
    float meanDot = msum / (float)deg;       // max(cnt,1) with deg>=1
    float x = g0[n] + r + meanDot;
    float gate = 1.f / (1.f + __expf(-x));
    out[outIdx] = gate * hk / fmaxf(denom, 1e-16f);
}

// ---------------------------------------------------------------------------
extern "C" void kernel_launch(void* const* d_in, const int* in_sizes, int n_in,
                              void* d_out, int out_size, void* d_ws, size_t ws_size,
                              hipStream_t stream)
{
    const float* v     = (const float*)d_in[0];
    const float* pre_w = (const float*)d_in[1];
    const int*   src   = (const int*)d_in[2];
    const int*   dst   = (const int*)d_in[3];
    const float* Wa    = (const float*)d_in[4];
    const float* a_l   = (const float*)d_in[5];
    const float* a_r   = (const float*)d_in[6];
    const float* Wg    = (const float*)d_in[7];
    const float* gl    = (const float*)d_in[8];
    const float* gm    = (const float*)d_in[9];
    const float* gr    = (const float*)d_in[10];
    int N = in_sizes[0] / DIM;
    int E = in_sizes[2];

    // workspace layout (~36.6 MB)
    float* ws   = (float*)d_ws;
    float* z    = ws;
    float* u    = z + (size_t)N * DIM;
    float* s_l  = u + (size_t)N * DIM;
    float* s_r  = s_l + N;
    float* t_gr = s_r + N;
    float* g0   = t_gr + N;
    int* cnt    = (int*)(g0 + N);
    int* offs   = cnt + N;
    int* cursor = offs + N;
    int* bsum   = cursor + N;
    int nb = (N + 1023) / 1024;
    int* src_s  = bsum + ((nb + 63) / 64) * 64;
    float* pw_s = (float*)(src_s + E);
    float* e_s  = pw_s + E;

    hipMemsetAsync(cnt, 0, (size_t)N * sizeof(int), stream);

    node_proj<<<(N + 255) / 256, 256, 0, stream>>>(
        v, Wa, Wg, a_l, a_r, gl, gr, z, u, s_l, s_r, t_gr, g0, N);

    count_edges<<<(E + 255) / 256, 256, 0, stream>>>(dst, cnt, E);
    scan_reduce<<<nb, 256, 0, stream>>>(cnt, bsum, N);
    scan_bsum<<<1, 64, 0, stream>>>(bsum, nb);
    scan_final<<<nb, 256, 0, stream>>>(cnt, bsum, offs, cursor, N);

    scatter_edges<<<(E + 255) / 256, 256, 0, stream>>>(
        src, dst, pre_w, s_l, s_r, cursor, src_s, pw_s, e_s, E);

    aggregate<<<(N + 3) / 4, 256, 0, stream>>>(
        offs, cnt, src_s, pw_s, e_s, z, u, t_gr, g0, gm, (float*)d_out, N);
}

// Round 2
// 316.601 us; speedup vs baseline: 1.1064x; 1.1064x over previous
//
#include <hip/hip_runtime.h>

#define DIM 64
#define SLOPE 0.01f
#define NB 64   // nodes per block in node_proj

// ---------------------------------------------------------------------------
// Kernel 1: per-node projections.
// Block = 256 threads = 4 waves, processes NB=64 nodes.
// v tile staged in LDS (16KB); lane k holds Wa row k and Wg row k in VGPRs
// (128 VGPRs by design -- no spill, unlike the round-1 per-thread version).
// Each wave walks 16 nodes; LDS reads are wave-broadcast (conflict-free).
// Outputs: z = v@Wa.T, u = v@Wg.T, s_l = z.a_l, s_r = z.a_r, t = v.gr, g0 = v.gl
// Stores are k-across-lanes -> 256B coalesced.
// ---------------------------------------------------------------------------
__global__ __launch_bounds__(256) void node_proj(
    const float* __restrict__ v, const float* __restrict__ Wa,
    const float* __restrict__ Wg, const float* __restrict__ a_l,
    const float* __restrict__ a_r, const float* __restrict__ gl,
    const float* __restrict__ gr,
    float* __restrict__ z, float* __restrict__ u,
    float* __restrict__ s_l, float* __restrict__ s_r,
    float* __restrict__ t_gr, float* __restrict__ g0, int N)
{
    __shared__ float vt[NB * DIM];            // 16 KB
    int tid = threadIdx.x;
    int base = blockIdx.x * NB;
    int nvalid = N - base; if (nvalid > NB) nvalid = NB;

    // coalesced float4 tile load (rows >= nvalid zero-filled)
    const float4* vsrc = (const float4*)(v + (size_t)base * DIM);
    float4* vdst = (float4*)vt;
    for (int i = tid; i < NB * DIM / 4; i += 256) {
        int row = i >> 4;                     // 16 float4 per row
        float4 q = make_float4(0.f, 0.f, 0.f, 0.f);
        if (row < nvalid) q = vsrc[i];
        vdst[i] = q;
    }
    __syncthreads();

    int k = tid & 63, g = tid >> 6;
    // per-lane weight rows in registers
    float wa[DIM], wg[DIM];
    const float4* wap = (const float4*)(Wa + k * DIM);
    const float4* wgp = (const float4*)(Wg + k * DIM);
#pragma unroll
    for (int i = 0; i < 16; i++) {
        float4 qa = wap[i], qg = wgp[i];
        wa[4*i+0]=qa.x; wa[4*i+1]=qa.y; wa[4*i+2]=qa.z; wa[4*i+3]=qa.w;
        wg[4*i+0]=qg.x; wg[4*i+1]=qg.y; wg[4*i+2]=qg.z; wg[4*i+3]=qg.w;
    }
    float alk = a_l[k], ark = a_r[k], grk = gr[k], glk = gl[k];

    for (int j = 0; j < NB / 4; j++) {
        int nl = g * (NB / 4) + j;
        int n = base + nl;
        if (n >= N) break;
        const float4* vrow = (const float4*)(vt + nl * DIM);
        float zk = 0.f, uk = 0.f;
#pragma unroll
        for (int i4 = 0; i4 < 16; i4++) {
            float4 q = vrow[i4];              // wave-broadcast LDS read
            zk += q.x * wa[4*i4+0] + q.y * wa[4*i4+1] + q.z * wa[4*i4+2] + q.w * wa[4*i4+3];
            uk += q.x * wg[4*i4+0] + q.y * wg[4*i4+1] + q.z * wg[4*i4+2] + q.w * wg[4*i4+3];
        }
        z[(size_t)n * DIM + k] = zk;          // 256B coalesced
        u[(size_t)n * DIM + k] = uk;
        float vk = vt[nl * DIM + k];          // stride-1 across lanes
        float r1 = zk * alk, r2 = zk * ark, r3 = vk * grk, r4 = vk * glk;
        for (int off = 32; off; off >>= 1) {
            r1 += __shfl_down(r1, off, 64);
            r2 += __shfl_down(r2, off, 64);
            r3 += __shfl_down(r3, off, 64);
            r4 += __shfl_down(r4, off, 64);
        }
        if (k == 0) { s_l[n] = r1; s_r[n] = r2; t_gr[n] = r3; g0[n] = r4; }
    }
}

// ---------------------------------------------------------------------------
// CSR build: count -> scan (3 small kernels) -> scatter
// ---------------------------------------------------------------------------
__global__ __launch_bounds__(256) void count_edges(
    const int* __restrict__ dst, int* __restrict__ cnt, int E)
{
    int e = blockIdx.x * 256 + threadIdx.x;
    if (e < E) atomicAdd(&cnt[dst[e]], 1);
}

__global__ __launch_bounds__(256) void scan_reduce(
    const int* __restrict__ cnt, int* __restrict__ bsum, int N)
{
    __shared__ int lds[256];
    int base = blockIdx.x * 1024;
    int s = 0;
    for (int i = threadIdx.x; i < 1024; i += 256) {
        int idx = base + i;
        if (idx < N) s += cnt[idx];
    }
    lds[threadIdx.x] = s;
    __syncthreads();
    for (int off = 128; off; off >>= 1) {
        if (threadIdx.x < off) lds[threadIdx.x] += lds[threadIdx.x + off];
        __syncthreads();
    }
    if (threadIdx.x == 0) bsum[blockIdx.x] = lds[0];
}

__global__ void scan_bsum(int* __restrict__ bsum, int nb)
{
    int i = threadIdx.x;
    int x = (i < nb) ? bsum[i] : 0;
    int incl = x;
    for (int off = 1; off < 64; off <<= 1) {
        int y = __shfl_up(incl, off, 64);
        if (i >= off) incl += y;
    }
    if (i < nb) bsum[i] = incl - x;
}

__global__ __launch_bounds__(256) void scan_final(
    const int* __restrict__ cnt, const int* __restrict__ bsum,
    int* __restrict__ offs, int* __restrict__ cursor, int N)
{
    __shared__ int lds[256];
    int base = blockIdx.x * 1024;
    int t = threadIdx.x;
    int idx0 = base + t * 4;
    int v4[4];
    int s = 0;
#pragma unroll
    for (int j = 0; j < 4; j++) {
        int idx = idx0 + j;
        int c = (idx < N) ? cnt[idx] : 0;
        v4[j] = s;
        s += c;
    }
    lds[t] = s;
    __syncthreads();
    for (int off = 1; off < 256; off <<= 1) {
        int y = (t >= off) ? lds[t - off] : 0;
        __syncthreads();
        lds[t] += y;
        __syncthreads();
    }
    int excl = lds[t] - s + bsum[blockIdx.x];
#pragma unroll
    for (int j = 0; j < 4; j++) {
        int idx = idx0 + j;
        if (idx < N) {
            int o = excl + v4[j];
            offs[idx] = o;
            cursor[idx] = o;
        }
    }
}

// scatter edges into CSR order; {src,pw} packed into one 8B store; edge
// attention score (leaky_relu) fused here.
__global__ __launch_bounds__(256) void scatter_edges(
    const int* __restrict__ src, const int* __restrict__ dst,
    const float* __restrict__ pre_w,
    const float* __restrict__ s_l, const float* __restrict__ s_r,
    int* __restrict__ cursor,
    int2* __restrict__ sp_s, float* __restrict__ e_s, int E)
{
    int e = blockIdx.x * 256 + threadIdx.x;
    if (e >= E) return;
    int s = src[e], d = dst[e];
    float pw = pre_w[e];
    int pos = atomicAdd(&cursor[d], 1);
    float ea = pw * s_l[s] + s_r[d];
    ea = ea > 0.f ? ea : SLOPE * ea;          // leaky_relu
    int2 sp; sp.x = s; sp.y = __float_as_int(pw);
    sp_s[pos] = sp;
    e_s[pos] = ea;
}

// ---------------------------------------------------------------------------
// Kernel: per-dst softmax -> overwrite e_s with alpha. One wave per node,
// lanes over edges. Removes exp + rescale chain from the aggregate loop.
// ---------------------------------------------------------------------------
__global__ __launch_bounds__(256) void edge_softmax(
    const int* __restrict__ offs, const int* __restrict__ cnt,
    float* __restrict__ e_s, int N)
{
    int wid = (blockIdx.x * 256 + threadIdx.x) >> 6;
    int lane = threadIdx.x & 63;
    if (wid >= N) return;
    int deg = cnt[wid];
    if (deg == 0) return;
    int start = offs[wid];
    float m = -INFINITY;
    for (int j = lane; j < deg; j += 64) m = fmaxf(m, e_s[start + j]);
    for (int off = 32; off; off >>= 1) m = fmaxf(m, __shfl_down(m, off, 64));
    m = __shfl(m, 0, 64);
    float ssum = 0.f;
    for (int j = lane; j < deg; j += 64) {
        float ex = __expf(e_s[start + j] - m);
        e_s[start + j] = ex;
        ssum += ex;
    }
    for (int off = 32; off; off >>= 1) ssum += __shfl_down(ssum, off, 64);
    ssum = __shfl(ssum, 0, 64);
    float inv = 1.f / fmaxf(ssum, 1e-16f);
    for (int j = lane; j < deg; j += 64) e_s[start + j] *= inv;
}

// ---------------------------------------------------------------------------
// Aggregate: one wave per dst node, lane = feature dim. Pure FMA/max
// accumulation, no loop-carried exp chain. Wave-uniform metadata goes
// through readfirstlane -> scalar loads, keeping the vector memory pipe
// free for the z/u gathers.
// ---------------------------------------------------------------------------
__global__ __launch_bounds__(256) void aggregate(
    const int* __restrict__ offs, const int* __restrict__ cnt,
    const int2* __restrict__ sp_s, const float* __restrict__ alpha_s,
    const float* __restrict__ z, const float* __restrict__ u,
    const float* __restrict__ t_gr, const float* __restrict__ g0,
    const float* __restrict__ gm,
    float* __restrict__ out, int N)
{
    int n = __builtin_amdgcn_readfirstlane((blockIdx.x * 256 + threadIdx.x) >> 6);
    int k = threadIdx.x & 63;
    if (n >= N) return;
    int deg = cnt[n];
    size_t outIdx = (size_t)n * DIM + k;
    if (deg == 0) { out[outIdx] = 0.f; return; }
    int start = offs[n];

    float hk = 0.f, mfk = -INFINITY, msum = 0.f;
    for (int j = 0; j < deg; j++) {
        int p = start + j;
        int2 sp = sp_s[p];                    // scalar load (uniform)
        int s = sp.x;
        float pw = __int_as_float(sp.y);
        float al = alpha_s[p];                // scalar load (uniform)
        float ts = t_gr[s];                   // scalar load (uniform)
        float zs = z[(size_t)s * DIM + k];    // 256B coalesced gather
        float us = u[(size_t)s * DIM + k];    // 256B coalesced gather
        hk = fmaf(al, zs, hk);
        mfk = fmaxf(mfk, pw * us);
        msum = fmaf(pw, ts, msum);
    }
    // wave reduction: maxFeat . gm
    float r = gm[k] * mfk;
    for (int off = 32; off; off >>= 1) r += __shfl_down(r, off, 64);
    r = __shfl(r, 0, 64);
    float meanDot = msum / (float)deg;
    float x = g0[n] + r + meanDot;
    float gate = 1.f / (1.f + __expf(-x));
    out[outIdx] = gate * hk;
}

// ---------------------------------------------------------------------------
extern "C" void kernel_launch(void* const* d_in, const int* in_sizes, int n_in,
                              void* d_out, int out_size, void* d_ws, size_t ws_size,
                              hipStream_t stream)
{
    const float* v     = (const float*)d_in[0];
    const float* pre_w = (const float*)d_in[1];
    const int*   src   = (const int*)d_in[2];
    const int*   dst   = (const int*)d_in[3];
    const float* Wa    = (const float*)d_in[4];
    const float* a_l   = (const float*)d_in[5];
    const float* a_r   = (const float*)d_in[6];
    const float* Wg    = (const float*)d_in[7];
    const float* gl    = (const float*)d_in[8];
    const float* gm    = (const float*)d_in[9];
    const float* gr    = (const float*)d_in[10];
    int N = in_sizes[0] / DIM;
    int E = in_sizes[2];

    // workspace layout (~36.5 MB)
    float* ws   = (float*)d_ws;
    float* z    = ws;
    float* u    = z + (size_t)N * DIM;
    float* s_l  = u + (size_t)N * DIM;
    float* s_r  = s_l + N;
    float* t_gr = s_r + N;
    float* g0   = t_gr + N;
    int* cnt    = (int*)(g0 + N);
    int* offs   = cnt + N;
    int* cursor = offs + N;
    int* bsum   = cursor + N;
    int nb = (N + 1023) / 1024;
    int2* sp_s  = (int2*)(bsum + ((nb + 63) / 64) * 64);
    float* e_s  = (float*)(sp_s + E);

    hipMemsetAsync(cnt, 0, (size_t)N * sizeof(int), stream);

    node_proj<<<(N + NB - 1) / NB, 256, 0, stream>>>(
        v, Wa, Wg, a_l, a_r, gl, gr, z, u, s_l, s_r, t_gr, g0, N);

    count_edges<<<(E + 255) / 256, 256, 0, stream>>>(dst, cnt, E);
    scan_reduce<<<nb, 256, 0, stream>>>(cnt, bsum, N);
    scan_bsum<<<1, 64, 0, stream>>>(bsum, nb);
    scan_final<<<nb, 256, 0, stream>>>(cnt, bsum, offs, cursor, N);

    scatter_edges<<<(E + 255) / 256, 256, 0, stream>>>(
        src, dst, pre_w, s_l, s_r, cursor, sp_s, e_s, E);

    edge_softmax<<<(N + 3) / 4, 256, 0, stream>>>(offs, cnt, e_s, N);

    aggregate<<<(N + 3) / 4, 256, 0, stream>>>(
        offs, cnt, sp_s, e_s, z, u, t_gr, g0, gm, (float*)d_out, N);
}

// Round 3
// 269.933 us; speedup vs baseline: 1.2977x; 1.1729x over previous
//
#include <hip/hip_runtime.h>
#include <hip/hip_fp16.h>

#define DIM 64
#define SLOPE 0.01f
#define NB 64   // nodes per block in node_proj

// ---------------------------------------------------------------------------
// Kernel 1: per-node projections.
// Block = 256 threads = 4 waves, NB=64 nodes. v tile in LDS; lane k holds
// Wa/Wg row k in registers. Outputs: packed fp16 table zu (x=z_k, y=u_k)
// and per-node fp32 scalars s_l = z.a_l, s_r = z.a_r, t = v.gr, g0 = v.gl.
// fp16 table halves the aggregate kernel's gather footprint (12.8MB total);
// scalars stay fp32 so the softmax logits are exact.
// ---------------------------------------------------------------------------
__global__ __launch_bounds__(256) void node_proj(
    const float* __restrict__ v, const float* __restrict__ Wa,
    const float* __restrict__ Wg, const float* __restrict__ a_l,
    const float* __restrict__ a_r, const float* __restrict__ gl,
    const float* __restrict__ gr,
    __half2* __restrict__ zu,
    float* __restrict__ s_l, float* __restrict__ s_r,
    float* __restrict__ t_gr, float* __restrict__ g0, int N)
{
    __shared__ float vt[NB * DIM];            // 16 KB
    int tid = threadIdx.x;
    int base = blockIdx.x * NB;
    int nvalid = N - base; if (nvalid > NB) nvalid = NB;

    const float4* vsrc = (const float4*)(v + (size_t)base * DIM);
    float4* vdst = (float4*)vt;
    for (int i = tid; i < NB * DIM / 4; i += 256) {
        int row = i >> 4;                     // 16 float4 per row
        float4 q = make_float4(0.f, 0.f, 0.f, 0.f);
        if (row < nvalid) q = vsrc[i];
        vdst[i] = q;
    }
    __syncthreads();

    int k = tid & 63, g = tid >> 6;
    float wa[DIM], wg[DIM];
    const float4* wap = (const float4*)(Wa + k * DIM);
    const float4* wgp = (const float4*)(Wg + k * DIM);
#pragma unroll
    for (int i = 0; i < 16; i++) {
        float4 qa = wap[i], qg = wgp[i];
        wa[4*i+0]=qa.x; wa[4*i+1]=qa.y; wa[4*i+2]=qa.z; wa[4*i+3]=qa.w;
        wg[4*i+0]=qg.x; wg[4*i+1]=qg.y; wg[4*i+2]=qg.z; wg[4*i+3]=qg.w;
    }
    float alk = a_l[k], ark = a_r[k], grk = gr[k], glk = gl[k];

    for (int j = 0; j < NB / 4; j++) {
        int nl = g * (NB / 4) + j;
        int n = base + nl;
        if (n >= N) break;
        const float4* vrow = (const float4*)(vt + nl * DIM);
        float zk = 0.f, uk = 0.f;
#pragma unroll
        for (int i4 = 0; i4 < 16; i4++) {
            float4 q = vrow[i4];              // wave-broadcast LDS read
            zk += q.x * wa[4*i4+0] + q.y * wa[4*i4+1] + q.z * wa[4*i4+2] + q.w * wa[4*i4+3];
            uk += q.x * wg[4*i4+0] + q.y * wg[4*i4+1] + q.z * wg[4*i4+2] + q.w * wg[4*i4+3];
        }
        zu[(size_t)n * DIM + k] = __floats2half2_rn(zk, uk);  // 256B coalesced
        float vk = vt[nl * DIM + k];
        float r1 = zk * alk, r2 = zk * ark, r3 = vk * grk, r4 = vk * glk;
        for (int off = 32; off; off >>= 1) {
            r1 += __shfl_down(r1, off, 64);
            r2 += __shfl_down(r2, off, 64);
            r3 += __shfl_down(r3, off, 64);
            r4 += __shfl_down(r4, off, 64);
        }
        if (k == 0) { s_l[n] = r1; s_r[n] = r2; t_gr[n] = r3; g0[n] = r4; }
    }
}

// ---------------------------------------------------------------------------
// CSR build: count -> scan (3 small kernels) -> scatter
// ---------------------------------------------------------------------------
__global__ __launch_bounds__(256) void count_edges(
    const int* __restrict__ dst, int* __restrict__ cnt, int E)
{
    int i = blockIdx.x * 256 + threadIdx.x;
    int e = i * 4;
    if (e + 3 < E) {
        int4 d = *(const int4*)(dst + e);
        atomicAdd(&cnt[d.x], 1); atomicAdd(&cnt[d.y], 1);
        atomicAdd(&cnt[d.z], 1); atomicAdd(&cnt[d.w], 1);
    } else {
        for (; e < E; e++) atomicAdd(&cnt[dst[e]], 1);
    }
}

__global__ __launch_bounds__(256) void scan_reduce(
    const int* __restrict__ cnt, int* __restrict__ bsum, int N)
{
    __shared__ int lds[256];
    int base = blockIdx.x * 1024;
    int s = 0;
    for (int i = threadIdx.x; i < 1024; i += 256) {
        int idx = base + i;
        if (idx < N) s += cnt[idx];
    }
    lds[threadIdx.x] = s;
    __syncthreads();
    for (int off = 128; off; off >>= 1) {
        if (threadIdx.x < off) lds[threadIdx.x] += lds[threadIdx.x + off];
        __syncthreads();
    }
    if (threadIdx.x == 0) bsum[blockIdx.x] = lds[0];
}

__global__ void scan_bsum(int* __restrict__ bsum, int nb)
{
    int i = threadIdx.x;
    int x = (i < nb) ? bsum[i] : 0;
    int incl = x;
    for (int off = 1; off < 64; off <<= 1) {
        int y = __shfl_up(incl, off, 64);
        if (i >= off) incl += y;
    }
    if (i < nb) bsum[i] = incl - x;
}

__global__ __launch_bounds__(256) void scan_final(
    const int* __restrict__ cnt, const int* __restrict__ bsum,
    int* __restrict__ offs, int* __restrict__ cursor, int N)
{
    __shared__ int lds[256];
    int base = blockIdx.x * 1024;
    int t = threadIdx.x;
    int idx0 = base + t * 4;
    int v4[4];
    int s = 0;
#pragma unroll
    for (int j = 0; j < 4; j++) {
        int idx = idx0 + j;
        int c = (idx < N) ? cnt[idx] : 0;
        v4[j] = s;
        s += c;
    }
    lds[t] = s;
    __syncthreads();
    for (int off = 1; off < 256; off <<= 1) {
        int y = (t >= off) ? lds[t - off] : 0;
        __syncthreads();
        lds[t] += y;
        __syncthreads();
    }
    int excl = lds[t] - s + bsum[blockIdx.x];
#pragma unroll
    for (int j = 0; j < 4; j++) {
        int idx = idx0 + j;
        if (idx < N) {
            int o = excl + v4[j];
            offs[idx] = o;
            cursor[idx] = o;
        }
    }
}

// scatter edges into CSR order; {src,pw} packed into one 8B store; edge
// attention score (leaky_relu, fp32 exact) fused here.
__global__ __launch_bounds__(256) void scatter_edges(
    const int* __restrict__ src, const int* __restrict__ dst,
    const float* __restrict__ pre_w,
    const float* __restrict__ s_l, const float* __restrict__ s_r,
    int* __restrict__ cursor,
    int2* __restrict__ sp_s, float* __restrict__ e_s, int E)
{
    int e = blockIdx.x * 256 + threadIdx.x;
    if (e >= E) return;
    int s = src[e], d = dst[e];
    float pw = pre_w[e];
    int pos = atomicAdd(&cursor[d], 1);
    float ea = pw * s_l[s] + s_r[d];
    ea = ea > 0.f ? ea : SLOPE * ea;          // leaky_relu
    int2 sp; sp.x = s; sp.y = __float_as_int(pw);
    sp_s[pos] = sp;
    e_s[pos] = ea;
}

// ---------------------------------------------------------------------------
// Per-dst softmax -> overwrite e_s with alpha. 16-lane subgroup per node
// (deg avg 16 -> 4x lane utilization vs one wave/node).
// ---------------------------------------------------------------------------
__global__ __launch_bounds__(256) void edge_softmax(
    const int* __restrict__ offs, const int* __restrict__ cnt,
    float* __restrict__ e_s, int N)
{
    int n = (blockIdx.x * 256 + threadIdx.x) >> 4;
    int lane = threadIdx.x & 15;
    if (n >= N) return;
    int deg = cnt[n];
    if (deg == 0) return;
    int start = offs[n];
    float m = -INFINITY;
    for (int j = lane; j < deg; j += 16) m = fmaxf(m, e_s[start + j]);
#pragma unroll
    for (int mask = 8; mask; mask >>= 1) m = fmaxf(m, __shfl_xor(m, mask, 64));
    float ssum = 0.f;
    for (int j = lane; j < deg; j += 16) {
        float ex = __expf(e_s[start + j] - m);
        e_s[start + j] = ex;
        ssum += ex;
    }
#pragma unroll
    for (int mask = 8; mask; mask >>= 1) ssum += __shfl_xor(ssum, mask, 64);
    float inv = 1.f / fmaxf(ssum, 1e-16f);
    for (int j = lane; j < deg; j += 16) e_s[start + j] *= inv;
}

// ---------------------------------------------------------------------------
// Aggregate: one wave per dst node, lane = feature dim. One packed 4B/lane
// gather per edge (fp16 z|u). Unrolled x4 so 4 gathers are in flight.
// Wave-uniform metadata goes through the scalar pipe.
// ---------------------------------------------------------------------------
__global__ __launch_bounds__(256) void aggregate(
    const int* __restrict__ offs, const int* __restrict__ cnt,
    const int2* __restrict__ sp_s, const float* __restrict__ alpha_s,
    const __half2* __restrict__ zu,
    const float* __restrict__ t_gr, const float* __restrict__ g0,
    const float* __restrict__ gm,
    float* __restrict__ out, int N)
{
    int n = __builtin_amdgcn_readfirstlane((blockIdx.x * 256 + threadIdx.x) >> 6);
    int k = threadIdx.x & 63;
    if (n >= N) return;
    int deg = cnt[n];
    size_t outIdx = (size_t)n * DIM + k;
    if (deg == 0) { out[outIdx] = 0.f; return; }
    int start = offs[n];

    float hk = 0.f, mfk = -INFINITY, msum = 0.f;
    int j = 0;
    for (; j + 4 <= deg; j += 4) {
        int p = start + j;
        int2 sp0 = sp_s[p+0], sp1 = sp_s[p+1], sp2 = sp_s[p+2], sp3 = sp_s[p+3];
        float al0 = alpha_s[p+0], al1 = alpha_s[p+1];
        float al2 = alpha_s[p+2], al3 = alpha_s[p+3];
        __half2 q0 = zu[(size_t)sp0.x * DIM + k];   // independent 256B gathers
        __half2 q1 = zu[(size_t)sp1.x * DIM + k];
        __half2 q2 = zu[(size_t)sp2.x * DIM + k];
        __half2 q3 = zu[(size_t)sp3.x * DIM + k];
        float pw0 = __int_as_float(sp0.y), pw1 = __int_as_float(sp1.y);
        float pw2 = __int_as_float(sp2.y), pw3 = __int_as_float(sp3.y);
        float t0 = t_gr[sp0.x], t1 = t_gr[sp1.x];
        float t2 = t_gr[sp2.x], t3 = t_gr[sp3.x];
        float2 f0 = __half22float2(q0), f1 = __half22float2(q1);
        float2 f2 = __half22float2(q2), f3 = __half22float2(q3);
        hk = fmaf(al0, f0.x, hk); mfk = fmaxf(mfk, pw0 * f0.y); msum = fmaf(pw0, t0, msum);
        hk = fmaf(al1, f1.x, hk); mfk = fmaxf(mfk, pw1 * f1.y); msum = fmaf(pw1, t1, msum);
        hk = fmaf(al2, f2.x, hk); mfk = fmaxf(mfk, pw2 * f2.y); msum = fmaf(pw2, t2, msum);
        hk = fmaf(al3, f3.x, hk); mfk = fmaxf(mfk, pw3 * f3.y); msum = fmaf(pw3, t3, msum);
    }
    for (; j < deg; j++) {
        int p = start + j;
        int2 sp = sp_s[p];
        float al = alpha_s[p];
        __half2 q = zu[(size_t)sp.x * DIM + k];
        float pw = __int_as_float(sp.y);
        float2 f = __half22float2(q);
        hk = fmaf(al, f.x, hk);
        mfk = fmaxf(mfk, pw * f.y);
        msum = fmaf(pw, t_gr[sp.x], msum);
    }
    // wave reduction: maxFeat . gm
    float r = gm[k] * mfk;
    for (int off = 32; off; off >>= 1) r += __shfl_down(r, off, 64);
    r = __shfl(r, 0, 64);
    float meanDot = msum / (float)deg;
    float x = g0[n] + r + meanDot;
    float gate = 1.f / (1.f + __expf(-x));
    out[outIdx] = gate * hk;
}

// ---------------------------------------------------------------------------
extern "C" void kernel_launch(void* const* d_in, const int* in_sizes, int n_in,
                              void* d_out, int out_size, void* d_ws, size_t ws_size,
                              hipStream_t stream)
{
    const float* v     = (const float*)d_in[0];
    const float* pre_w = (const float*)d_in[1];
    const int*   src   = (const int*)d_in[2];
    const int*   dst   = (const int*)d_in[3];
    const float* Wa    = (const float*)d_in[4];
    const float* a_l   = (const float*)d_in[5];
    const float* a_r   = (const float*)d_in[6];
    const float* Wg    = (const float*)d_in[7];
    const float* gl    = (const float*)d_in[8];
    const float* gm    = (const float*)d_in[9];
    const float* gr    = (const float*)d_in[10];
    int N = in_sizes[0] / DIM;
    int E = in_sizes[2];

    // workspace layout (~24 MB)
    char* ws   = (char*)d_ws;
    __half2* zu = (__half2*)ws;                       // N*DIM*4B = 12.8MB
    float* s_l  = (float*)(ws + (size_t)N * DIM * 4);
    float* s_r  = s_l + N;
    float* t_gr = s_r + N;
    float* g0   = t_gr + N;
    int* cnt    = (int*)(g0 + N);
    int* offs   = cnt + N;
    int* cursor = offs + N;
    int* bsum   = cursor + N;
    int nb = (N + 1023) / 1024;
    int2* sp_s  = (int2*)(bsum + ((nb + 63) / 64) * 64);
    float* e_s  = (float*)(sp_s + E);

    hipMemsetAsync(cnt, 0, (size_t)N * sizeof(int), stream);

    node_proj<<<(N + NB - 1) / NB, 256, 0, stream>>>(
        v, Wa, Wg, a_l, a_r, gl, gr, zu, s_l, s_r, t_gr, g0, N);

    count_edges<<<(E / 4 + 255) / 256, 256, 0, stream>>>(dst, cnt, E);
    scan_reduce<<<nb, 256, 0, stream>>>(cnt, bsum, N);
    scan_bsum<<<1, 64, 0, stream>>>(bsum, nb);
    scan_final<<<nb, 256, 0, stream>>>(cnt, bsum, offs, cursor, N);

    scatter_edges<<<(E + 255) / 256, 256, 0, stream>>>(
        src, dst, pre_w, s_l, s_r, cursor, sp_s, e_s, E);

    edge_softmax<<<(N * 16 + 255) / 256, 256, 0, stream>>>(offs, cnt, e_s, N);

    aggregate<<<(N + 3) / 4, 256, 0, stream>>>(
        offs, cnt, sp_s, e_s, zu, t_gr, g0, gm, (float*)d_out, N);
}